// Round 1
// baseline (339.376 us; speedup 1.0000x reference)
//
#include <hip/hip_runtime.h>

#define EPSF 1e-5f

// ---------- ws layout ----------
// qh1 : int8  [32*576*784] = 14450688 B   (quantized conv1 output)
// qh2 : int8  [32*576*784] = 14450688 B   (quantized dw output)
// w1q : f32   [576*96]                    (quantized w1 values)
// w2q : f32   [576*9]
// w3q : f32   [96*576]
#define QH1_OFF 0
#define QH2_OFF 14450688
#define W1Q_OFF 28901376
#define W2Q_OFF (W1Q_OFF + 55296*4)
#define W3Q_OFF (W2Q_OFF + 5184*4)

__device__ __forceinline__ float lsq_q(float v, float a) {
    float t = v / a;                       // real division: match reference rounding
    t = fminf(fmaxf(t, -8.0f), 7.0f);
    return rintf(t);                       // RNE == jnp.round
}

// ---------------- kernel 0: quantize weights ----------------
__global__ __launch_bounds__(256)
void quant_w_k(const float* __restrict__ w1, const float* __restrict__ w2,
               const float* __restrict__ w3,
               const float* aw1, const float* aw2, const float* aw3,
               float* __restrict__ w1q, float* __restrict__ w2q,
               float* __restrict__ w3q) {
    int i = blockIdx.x * 256 + threadIdx.x;   // grid covers 55296
    if (i < 55296) w1q[i] = lsq_q(w1[i], aw1[0]);
    if (i < 5184)  w2q[i] = lsq_q(w2[i], aw2[0]);
    if (i < 55296) w3q[i] = lsq_q(w3[i], aw3[0]);
}

// ---------------- kernel 1: 1x1 expand conv (GEMM 576x96 @ 96xN) ----------------
// grid (392 n-tiles, 9 co-tiles), block 256. Tile: 64 co x 64 n, K=96 staged once.
__global__ __launch_bounds__(256)
void conv1_k(const float* __restrict__ x, const float* __restrict__ w1q,
             const float* ax1, const float* aw1, const float* ax2,
             const float* __restrict__ g1, const float* __restrict__ b1,
             const float* __restrict__ m1, const float* __restrict__ v1,
             signed char* __restrict__ qh1) {
    __shared__ float sA[96 * 64];   // sA[ci][co_r]
    __shared__ float sB[96 * 64];   // sB[ci][n_r]
    const int tid = threadIdx.x;
    const int n0  = blockIdx.x * 64;
    const int co0 = blockIdx.y * 64;
    const float ax1v = ax1[0];

    // stage quantized weight tile: e -> co_r = e%64 (lane-contig LDS), ci = e/64
    for (int e = tid; e < 6144; e += 256) {
        int co_r = e & 63, ci = e >> 6;
        sA[ci * 64 + co_r] = w1q[(co0 + co_r) * 96 + ci];
    }
    // stage quantized x tile: e -> n_r = e%64 (coalesced global), ci = e/64
    for (int e = tid; e < 6144; e += 256) {
        int n_r = e & 63, ci = e >> 6;
        int n = n0 + n_r;
        int bi = n / 784, p = n % 784;
        float xv = x[(bi * 96 + ci) * 784 + p];
        sB[ci * 64 + n_r] = lsq_q(xv, ax1v);
    }
    __syncthreads();

    const int tx = tid & 15, ty = tid >> 4;
    float acc[4][4] = {};
    #pragma unroll 4
    for (int k = 0; k < 96; ++k) {
        float a[4], b[4];
        #pragma unroll
        for (int i = 0; i < 4; ++i) a[i] = sA[k * 64 + ty * 4 + i];
        #pragma unroll
        for (int j = 0; j < 4; ++j) b[j] = sB[k * 64 + tx * 4 + j];
        #pragma unroll
        for (int i = 0; i < 4; ++i)
            #pragma unroll
            for (int j = 0; j < 4; ++j)
                acc[i][j] += a[i] * b[j];
    }

    // epilogue: scale, BN, ReLU6, requant by ax2 -> int8
    const float A = aw1[0] * ax1v;
    const float ax2v = ax2[0];
    const int n_base = n0 + tx * 4;          // group of 4 never crosses batch (784%4==0)
    const int bi = n_base / 784, p0 = n_base % 784;
    #pragma unroll
    for (int i = 0; i < 4; ++i) {
        int co = co0 + ty * 4 + i;
        float s  = g1[co] / sqrtf(v1[co] + EPSF);
        float mm = m1[co], bv = b1[co];
        int q[4];
        #pragma unroll
        for (int j = 0; j < 4; ++j) {
            float val = acc[i][j] * A;
            val = (val - mm) * s + bv;
            val = fminf(fmaxf(val, 0.0f), 6.0f);
            q[j] = (int)lsq_q(val, ax2v);
        }
        int pk = (q[0] & 255) | ((q[1] & 255) << 8) | ((q[2] & 255) << 16) | ((q[3] & 255) << 24);
        *(int*)(qh1 + (bi * 576 + co) * 784 + p0) = pk;
    }
}

// ---------------- kernel 2: 3x3 depthwise conv ----------------
// one thread per output element; idx == (bb*576 + c)*784 + p
__global__ __launch_bounds__(256)
void dw_k(const signed char* __restrict__ qh1, const float* __restrict__ w2q,
          const float* ax2, const float* aw2, const float* ax3,
          const float* __restrict__ g2, const float* __restrict__ b2,
          const float* __restrict__ m2, const float* __restrict__ v2,
          signed char* __restrict__ qh2) {
    int idx = blockIdx.x * 256 + threadIdx.x;   // grid covers 14450688 exactly
    int p = idx % 784;
    int t = idx / 784;          // bb*576 + c
    int c = t % 576;
    int hh = p / 28, ww = p % 28;
    const signed char* base = qh1 + t * 784;

    float wv[9];
    #pragma unroll
    for (int i = 0; i < 9; ++i) wv[i] = w2q[c * 9 + i];

    float acc = 0.0f;
    #pragma unroll
    for (int kh = 0; kh < 3; ++kh) {
        int ih = hh + kh - 1;
        if (ih < 0 || ih >= 28) continue;
        #pragma unroll
        for (int kw = 0; kw < 3; ++kw) {
            int iw = ww + kw - 1;
            if (iw < 0 || iw >= 28) continue;
            acc += (float)base[ih * 28 + iw] * wv[kh * 3 + kw];
        }
    }
    float val = acc * (ax2[0] * aw2[0]);
    float s = g2[c] / sqrtf(v2[c] + EPSF);
    val = (val - m2[c]) * s + b2[c];
    val = fminf(fmaxf(val, 0.0f), 6.0f);
    qh2[idx] = (signed char)(int)lsq_q(val, ax3[0]);
}

// ---------------- kernel 3: 1x1 project conv + BN + residual ----------------
// grid 392 n-tiles, block 256. Tile: all 96 co x 64 n, K loop 9 x 64.
__global__ __launch_bounds__(256)
void conv3_k(const signed char* __restrict__ qh2, const float* __restrict__ w3q,
             const float* __restrict__ x,
             const float* ax3, const float* aw3,
             const float* __restrict__ g3, const float* __restrict__ b3,
             const float* __restrict__ m3, const float* __restrict__ v3,
             float* __restrict__ out) {
    __shared__ float sW[64 * 96];   // sW[kk][co]
    __shared__ float sX[64 * 64];   // sX[kk][n_r]
    const int tid = threadIdx.x;
    const int n0 = blockIdx.x * 64;
    const int tx = tid & 15, ty = tid >> 4;

    float acc[6][4] = {};
    for (int k0 = 0; k0 < 576; k0 += 64) {
        // stage quantized w3 tile: e -> co = e%96 (lane-contig LDS write), kk = e/96
        for (int e = tid; e < 6144; e += 256) {
            int co = e % 96, kk = e / 96;
            sW[kk * 96 + co] = w3q[co * 576 + k0 + kk];
        }
        // stage int8 activations: e -> n_r = e&63 (coalesced), kk = e>>6
        for (int e = tid; e < 4096; e += 256) {
            int n_r = e & 63, kk = e >> 6;
            int n = n0 + n_r;
            int bi = n / 784, p = n % 784;
            sX[kk * 64 + n_r] = (float)qh2[(bi * 576 + k0 + kk) * 784 + p];
        }
        __syncthreads();
        #pragma unroll 4
        for (int kk = 0; kk < 64; ++kk) {
            float a[6], b[4];
            #pragma unroll
            for (int i = 0; i < 6; ++i) a[i] = sW[kk * 96 + ty * 6 + i];
            #pragma unroll
            for (int j = 0; j < 4; ++j) b[j] = sX[kk * 64 + tx * 4 + j];
            #pragma unroll
            for (int i = 0; i < 6; ++i)
                #pragma unroll
                for (int j = 0; j < 4; ++j)
                    acc[i][j] += a[i] * b[j];
        }
        __syncthreads();
    }

    const float A = ax3[0] * aw3[0];
    const int n_base = n0 + tx * 4;
    const int bi = n_base / 784, p0 = n_base % 784;
    #pragma unroll
    for (int i = 0; i < 6; ++i) {
        int co = ty * 6 + i;
        float s  = g3[co] / sqrtf(v3[co] + EPSF);
        float mm = m3[co], bv = b3[co];
        #pragma unroll
        for (int j = 0; j < 4; ++j) {
            float val = acc[i][j] * A;
            val = (val - mm) * s + bv;
            int off = (bi * 96 + co) * 784 + p0 + j;
            out[off] = val + x[off];
        }
    }
}

extern "C" void kernel_launch(void* const* d_in, const int* in_sizes, int n_in,
                              void* d_out, int out_size, void* d_ws, size_t ws_size,
                              hipStream_t stream) {
    const float* x   = (const float*)d_in[0];
    const float* w1  = (const float*)d_in[1];
    const float* w2  = (const float*)d_in[2];
    const float* w3  = (const float*)d_in[3];
    const float* aw1 = (const float*)d_in[4];
    const float* ax1 = (const float*)d_in[5];
    const float* g1  = (const float*)d_in[6];
    const float* b1  = (const float*)d_in[7];
    const float* m1  = (const float*)d_in[8];
    const float* v1  = (const float*)d_in[9];
    const float* aw2 = (const float*)d_in[10];
    const float* ax2 = (const float*)d_in[11];
    const float* g2  = (const float*)d_in[12];
    const float* b2  = (const float*)d_in[13];
    const float* m2  = (const float*)d_in[14];
    const float* v2  = (const float*)d_in[15];
    const float* aw3 = (const float*)d_in[16];
    const float* ax3 = (const float*)d_in[17];
    const float* g3  = (const float*)d_in[18];
    const float* b3  = (const float*)d_in[19];
    const float* m3  = (const float*)d_in[20];
    const float* v3  = (const float*)d_in[21];

    char* ws = (char*)d_ws;
    signed char* qh1 = (signed char*)(ws + QH1_OFF);
    signed char* qh2 = (signed char*)(ws + QH2_OFF);
    float* w1q = (float*)(ws + W1Q_OFF);
    float* w2q = (float*)(ws + W2Q_OFF);
    float* w3q = (float*)(ws + W3Q_OFF);

    float* out = (float*)d_out;

    quant_w_k<<<216, 256, 0, stream>>>(w1, w2, w3, aw1, aw2, aw3, w1q, w2q, w3q);
    dim3 grid1(392, 9);
    conv1_k<<<grid1, 256, 0, stream>>>(x, w1q, ax1, aw1, ax2, g1, b1, m1, v1, qh1);
    dw_k<<<56448, 256, 0, stream>>>(qh1, w2q, ax2, aw2, ax3, g2, b2, m2, v2, qh2);
    conv3_k<<<392, 256, 0, stream>>>(qh2, w3q, x, ax3, aw3, g3, b3, m3, v3, out);
}

// Round 2
// 189.641 us; speedup vs baseline: 1.7896x; 1.7896x over previous
//
#include <hip/hip_runtime.h>

#define EPSF 1e-5f

typedef int int4v __attribute__((ext_vector_type(4)));

// ---------- ws layout ----------
// qh1T : int8 [25088][576] = 14450688 B   (conv1 out, quantized, n-major)
// qh2T : int8 [25088][576] = 14450688 B   (dw out, quantized, n-major)
// w1p  : i64  [36*3*64]    = 55296 B      (w1 packed B-fragments)
// w3p  : i64  [6*18*64]    = 55296 B      (w3 packed B-fragments)
// w2qi : int8 [9][576]     = 5184 B       (dw weights, tap-major)
#define QH1T_OFF 0
#define QH2T_OFF 14450688
#define W1P_OFF  28901376
#define W3P_OFF  (W1P_OFF + 55296)
#define W2QI_OFF (W3P_OFF + 55296)

__device__ __forceinline__ float lsq_q(float v, float a) {
    float t = v / a;                       // exact division: match reference rounding
    t = fminf(fmaxf(t, -8.0f), 7.0f);
    return rintf(t);                       // RNE == jnp.round
}

__device__ __forceinline__ long q8pack(const float* s, int stride, float a) {
    unsigned long long v = 0;
    #pragma unroll
    for (int j = 0; j < 8; ++j) {
        int q = (int)lsq_q(s[j * stride], a);
        v |= (unsigned long long)(q & 255) << (8 * j);
    }
    return (long)v;
}

// ---------------- prep: quantize + fragment-pack all weights ----------------
// B-fragment layout for mfma_i32_16x16x32_i8: lane l holds B[k][n'] with
// n' = l&15, k = (l>>4)*8 + j  (j = byte index, little-endian in the i64).
__global__ __launch_bounds__(256)
void prep_w(const float* __restrict__ w1, const float* __restrict__ w2,
            const float* __restrict__ w3,
            const float* aw1, const float* aw2, const float* aw3,
            long* __restrict__ w1p, long* __restrict__ w3p,
            signed char* __restrict__ w2qi) {
    int id = blockIdx.x * 256 + threadIdx.x;
    if (id < 6912) {                        // w1p: tile ct 0..35, kc 0..2
        int l = id & 63, t = id >> 6;
        int kc = t % 3, ct = t / 3;
        int co = ct * 16 + (l & 15);
        int ci0 = kc * 32 + (l >> 4) * 8;
        w1p[id] = q8pack(w1 + co * 96 + ci0, 1, aw1[0]);
    } else if (id < 13824) {                // w3p: tile ct 0..5, kc 0..17
        int i = id - 6912;
        int l = i & 63, t = i >> 6;
        int kc = t % 18, ct = t / 18;
        int co = ct * 16 + (l & 15);
        int ci0 = kc * 32 + (l >> 4) * 8;
        w3p[i] = q8pack(w3 + co * 576 + ci0, 1, aw3[0]);
    } else if (id < 19008) {                // w2qi[tap][c]
        int i = id - 13824;
        int c = i % 576, tap = i / 576;
        w2qi[i] = (signed char)(int)lsq_q(w2[c * 9 + tap], aw2[0]);
    }
}

// ---------------- conv1: 1x1 expand as i8 MFMA GEMM ----------------
// D[n][co] = X[n][k=96] @ W1^T[k][co].  A-frags: on-the-fly quantized x.
// grid (392 n-strips of 64, 3 co-strips of 192), block 256 (4 waves).
// wave w: n-tile = n0 + w*16, 12 co-tiles, K = 3 chunks of 32.  No LDS.
__global__ __launch_bounds__(256)
void conv1_mfma(const float* __restrict__ x, const long* __restrict__ w1p,
                const float* ax1, const float* aw1, const float* ax2,
                const float* __restrict__ g1, const float* __restrict__ b1,
                const float* __restrict__ m1, const float* __restrict__ v1,
                signed char* __restrict__ qh1T) {
    const int tid = threadIdx.x;
    const int w = tid >> 6, l = tid & 63;
    const int quad = l >> 4;
    const int n0 = blockIdx.x * 64;
    const int cs = blockIdx.y;              // co base = cs*192
    const float ax1v = ax1[0];

    const int n_m = n0 + w * 16 + (l & 15); // A-row (m = lane&15)
    const int bi = n_m / 784, p = n_m % 784;

    int4v acc[12];
    #pragma unroll
    for (int i = 0; i < 12; ++i) { acc[i][0] = 0; acc[i][1] = 0; acc[i][2] = 0; acc[i][3] = 0; }

    #pragma unroll
    for (int kc = 0; kc < 3; ++kc) {
        // A frag: 8 channels (kc*32 + quad*8 ..+7) of position n_m, quantized
        const float* xs = x + (bi * 96 + kc * 32 + quad * 8) * 784 + p;
        long a = q8pack(xs, 784, ax1v);
        #pragma unroll
        for (int ct = 0; ct < 12; ++ct) {
            long b = w1p[((cs * 12 + ct) * 3 + kc) * 64 + l];
            acc[ct] = __builtin_amdgcn_mfma_i32_16x16x32_i8(a, b, acc[ct], 0, 0, 0);
        }
    }

    const float A = aw1[0] * ax1v;
    const float ax2v = ax2[0];
    const int n_base = n0 + w * 16 + quad * 4;     // + reg
    #pragma unroll
    for (int ct = 0; ct < 12; ++ct) {
        int co = cs * 192 + ct * 16 + (l & 15);
        float s  = g1[co] / sqrtf(v1[co] + EPSF);
        float mm = m1[co], bv = b1[co];
        #pragma unroll
        for (int r = 0; r < 4; ++r) {
            float val = (float)acc[ct][r] * A;
            val = (val - mm) * s + bv;
            val = fminf(fmaxf(val, 0.0f), 6.0f);
            qh1T[(n_base + r) * 576 + co] = (signed char)(int)lsq_q(val, ax2v);
        }
    }
}

// ---------------- dw: 3x3 depthwise, exact int math, [n][c] layout ----------------
// thread -> (n, g): 4 channels c = 4g..4g+3.  int32 loads, coalesced.
__global__ __launch_bounds__(256)
void dw_k(const signed char* __restrict__ qh1T, const signed char* __restrict__ w2qi,
          const float* ax2, const float* aw2, const float* ax3,
          const float* __restrict__ g2, const float* __restrict__ b2,
          const float* __restrict__ m2, const float* __restrict__ v2,
          signed char* __restrict__ qh2T) {
    int idx = blockIdx.x * 256 + threadIdx.x;   // 25088*144 exactly
    int n = idx / 144, g = idx % 144;
    int p = n % 784;
    int hh = p / 28, ww = p % 28;
    const signed char* base = qh1T + n * 576 + 4 * g;

    int wv[9];
    #pragma unroll
    for (int t = 0; t < 9; ++t)
        wv[t] = *(const int*)(w2qi + t * 576 + 4 * g);

    int acc0 = 0, acc1 = 0, acc2 = 0, acc3 = 0;
    #pragma unroll
    for (int dh = -1; dh <= 1; ++dh) {
        int ih = hh + dh;
        if (ih < 0 || ih >= 28) continue;
        #pragma unroll
        for (int dw = -1; dw <= 1; ++dw) {
            int iw = ww + dw;
            if (iw < 0 || iw >= 28) continue;
            int xi = *(const int*)(base + (dh * 28 + dw) * 576);
            int wi = wv[(dh + 1) * 3 + (dw + 1)];
            acc0 += ((xi << 24) >> 24) * ((wi << 24) >> 24);
            acc1 += ((xi << 16) >> 24) * ((wi << 16) >> 24);
            acc2 += ((xi << 8)  >> 24) * ((wi << 8)  >> 24);
            acc3 += (xi >> 24)         * (wi >> 24);
        }
    }

    const float AA = ax2[0] * aw2[0];
    const float ax3v = ax3[0];
    int accs[4] = {acc0, acc1, acc2, acc3};
    int pk = 0;
    #pragma unroll
    for (int j = 0; j < 4; ++j) {
        int c = 4 * g + j;
        float val = (float)accs[j] * AA;
        float s = g2[c] / sqrtf(v2[c] + EPSF);
        val = (val - m2[c]) * s + b2[c];
        val = fminf(fmaxf(val, 0.0f), 6.0f);
        int q = (int)lsq_q(val, ax3v);
        pk |= (q & 255) << (8 * j);
    }
    *(int*)(qh2T + n * 576 + 4 * g) = pk;
}

// ---------------- conv3: 1x1 project as i8 MFMA GEMM + BN + residual ----------------
// D[n][co=96] = H[n][k=576] @ W3^T[k][co].  grid 1568 n-tiles of 16, block 384
// (6 waves; wave w = co-tile w).  A-frags direct from qh2T, B from packed w3p.
__global__ __launch_bounds__(384)
void conv3_mfma(const signed char* __restrict__ qh2T, const long* __restrict__ w3p,
                const float* __restrict__ x,
                const float* ax3, const float* aw3,
                const float* __restrict__ g3, const float* __restrict__ b3,
                const float* __restrict__ m3, const float* __restrict__ v3,
                float* __restrict__ out) {
    const int tid = threadIdx.x;
    const int w = tid >> 6, l = tid & 63;
    const int quad = l >> 4;
    const int n0 = blockIdx.x * 16;
    const int n_m = n0 + (l & 15);

    int4v acc;
    acc[0] = 0; acc[1] = 0; acc[2] = 0; acc[3] = 0;

    const signed char* arow = qh2T + n_m * 576 + quad * 8;
    #pragma unroll 6
    for (int kc = 0; kc < 18; ++kc) {
        long a = *(const long*)(arow + kc * 32);
        long b = w3p[(w * 18 + kc) * 64 + l];
        acc = __builtin_amdgcn_mfma_i32_16x16x32_i8(a, b, acc, 0, 0, 0);
    }

    const float A = ax3[0] * aw3[0];
    const int co = w * 16 + (l & 15);
    const float s  = g3[co] / sqrtf(v3[co] + EPSF);
    const float mm = m3[co], bv = b3[co];
    #pragma unroll
    for (int r = 0; r < 4; ++r) {
        int n = n0 + quad * 4 + r;
        int bi = n / 784, p = n % 784;
        int off = (bi * 96 + co) * 784 + p;
        float val = (float)acc[r] * A;
        val = (val - mm) * s + bv;
        out[off] = val + x[off];
    }
}

extern "C" void kernel_launch(void* const* d_in, const int* in_sizes, int n_in,
                              void* d_out, int out_size, void* d_ws, size_t ws_size,
                              hipStream_t stream) {
    const float* x   = (const float*)d_in[0];
    const float* w1  = (const float*)d_in[1];
    const float* w2  = (const float*)d_in[2];
    const float* w3  = (const float*)d_in[3];
    const float* aw1 = (const float*)d_in[4];
    const float* ax1 = (const float*)d_in[5];
    const float* g1  = (const float*)d_in[6];
    const float* b1  = (const float*)d_in[7];
    const float* m1  = (const float*)d_in[8];
    const float* v1  = (const float*)d_in[9];
    const float* aw2 = (const float*)d_in[10];
    const float* ax2 = (const float*)d_in[11];
    const float* g2  = (const float*)d_in[12];
    const float* b2  = (const float*)d_in[13];
    const float* m2  = (const float*)d_in[14];
    const float* v2  = (const float*)d_in[15];
    const float* aw3 = (const float*)d_in[16];
    const float* ax3 = (const float*)d_in[17];
    const float* g3  = (const float*)d_in[18];
    const float* b3  = (const float*)d_in[19];
    const float* m3  = (const float*)d_in[20];
    const float* v3  = (const float*)d_in[21];

    char* ws = (char*)d_ws;
    signed char* qh1T = (signed char*)(ws + QH1T_OFF);
    signed char* qh2T = (signed char*)(ws + QH2T_OFF);
    long* w1p  = (long*)(ws + W1P_OFF);
    long* w3p  = (long*)(ws + W3P_OFF);
    signed char* w2qi = (signed char*)(ws + W2QI_OFF);

    float* out = (float*)d_out;

    prep_w<<<75, 256, 0, stream>>>(w1, w2, w3, aw1, aw2, aw3, w1p, w3p, w2qi);
    dim3 grid1(392, 3);
    conv1_mfma<<<grid1, 256, 0, stream>>>(x, w1p, ax1, aw1, ax2, g1, b1, m1, v1, qh1T);
    dw_k<<<14112, 256, 0, stream>>>(qh1T, w2qi, ax2, aw2, ax3, g2, b2, m2, v2, qh2T);
    conv3_mfma<<<1568, 384, 0, stream>>>(qh2T, w3p, x, ax3, aw3, g3, b3, m3, v3, out);
}

// Round 3
// 163.089 us; speedup vs baseline: 2.0809x; 1.1628x over previous
//
#include <hip/hip_runtime.h>

#define EPSF 1e-5f

typedef int      int4v   __attribute__((ext_vector_type(4)));
typedef int      int2v   __attribute__((ext_vector_type(2)));
typedef float    float4v __attribute__((ext_vector_type(4)));
typedef _Float16 half8   __attribute__((ext_vector_type(8)));
typedef _Float16 half4   __attribute__((ext_vector_type(4)));

// ---------- ws layout ----------
// qh1h : half [25088][576] = 28901376 B  (conv1 out, quantized ints, fp16)
// qh2T : int8 [25088][576] = 14450688 B  (dw out, quantized, n-major)
// w1p  : i64  [36*3*64]                  (w1 packed MFMA A-fragments)
// w3p  : i64  [6*18*64]                  (w3 packed MFMA B-fragments)
// w2h  : half [9][576]                   (dw weights, tap-major, fp16)
// s1b1 : f32  [2][576]   fused epilogue scale/bias for conv1
// s2b2 : f32  [2][576]   for dw
// s3b3 : f32  [2][96]    for conv3
#define QH1H_OFF 0
#define QH2T_OFF 28901376
#define W1P_OFF  43352064
#define W3P_OFF  (W1P_OFF + 55296)
#define W2H_OFF  (W3P_OFF + 55296)
#define S1B1_OFF (W2H_OFF + 10368)
#define S2B2_OFF (S1B1_OFF + 4608)
#define S3B3_OFF (S2B2_OFF + 4608)

__device__ __forceinline__ float lsq_q(float v, float a) {
    float t = v / a;                       // real division (weights: a not pow2)
    t = fminf(fmaxf(t, -8.0f), 7.0f);
    return rintf(t);                       // RNE == jnp.round
}

__device__ __forceinline__ long q8pack_w(const float* s, float a) {
    unsigned long long v = 0;
    #pragma unroll
    for (int j = 0; j < 8; ++j) {
        int q = (int)lsq_q(s[j], a);
        v |= (unsigned long long)(q & 255) << (8 * j);
    }
    return (long)v;
}

// ---------------- prep: quantize/pack weights + fused epilogue constants ----------------
// Fragment layout (16x16x32 i8, verified end-to-end r2): lane l holds 8 k-bytes
// k = (l>>4)*8 + j at m/n' = l&15.
__global__ __launch_bounds__(256)
void prep_w(const float* __restrict__ w1, const float* __restrict__ w2,
            const float* __restrict__ w3,
            const float* aw1, const float* ax1, const float* ax2,
            const float* aw2, const float* ax3, const float* aw3,
            const float* __restrict__ g1, const float* __restrict__ b1,
            const float* __restrict__ m1, const float* __restrict__ v1,
            const float* __restrict__ g2, const float* __restrict__ b2,
            const float* __restrict__ m2, const float* __restrict__ v2,
            const float* __restrict__ g3, const float* __restrict__ b3,
            const float* __restrict__ m3, const float* __restrict__ v3,
            long* __restrict__ w1p, long* __restrict__ w3p,
            _Float16* __restrict__ w2h,
            float* __restrict__ s1b1, float* __restrict__ s2b2,
            float* __restrict__ s3b3) {
    int id = blockIdx.x * 256 + threadIdx.x;
    if (id < 6912) {                        // w1p: ct 0..35, kc 0..2
        int l = id & 63, t = id >> 6;
        int kc = t % 3, ct = t / 3;
        int co = ct * 16 + (l & 15);
        int ci0 = kc * 32 + (l >> 4) * 8;
        w1p[id] = q8pack_w(w1 + co * 96 + ci0, aw1[0]);
    } else if (id < 13824) {                // w3p: ct 0..5, kc 0..17
        int i = id - 6912;
        int l = i & 63, t = i >> 6;
        int kc = t % 18, ct = t / 18;
        int co = ct * 16 + (l & 15);
        int ci0 = kc * 32 + (l >> 4) * 8;
        w3p[i] = q8pack_w(w3 + co * 576 + ci0, aw3[0]);
    } else if (id < 19008) {                // w2h[tap][c], fp16 (exact small ints)
        int i = id - 13824;
        int c = i % 576, tap = i / 576;
        w2h[i] = (_Float16)lsq_q(w2[c * 9 + tap], aw2[0]);
    } else if (id < 19584) {                // conv1 fused constants
        int c = id - 19008;
        float s = g1[c] / sqrtf(v1[c] + EPSF);
        float A = aw1[0] * ax1[0];
        float inv = 1.0f / ax2[0];          // exact (alpha = pow2)
        s1b1[c] = A * s * inv;
        s1b1[576 + c] = (b1[c] - m1[c] * s) * inv;
    } else if (id < 20160) {                // dw fused constants
        int c = id - 19584;
        float s = g2[c] / sqrtf(v2[c] + EPSF);
        float A = ax2[0] * aw2[0];
        float inv = 1.0f / ax3[0];
        s2b2[c] = A * s * inv;
        s2b2[576 + c] = (b2[c] - m2[c] * s) * inv;
    } else if (id < 20256) {                // conv3 fused constants (no requant)
        int c = id - 20160;
        float s = g3[c] / sqrtf(v3[c] + EPSF);
        float A = ax3[0] * aw3[0];
        s3b3[c] = A * s;
        s3b3[96 + c] = b3[c] - m3[c] * s;
    }
}

// ---------------- conv1: 1x1 expand, i8 MFMA, A=weights B=acts ----------------
// grid (392 n-strips of 64, 3 co-strips of 192), block 256 (wave w -> 16 n).
// D rows = co (quad*4+reg -> 4 consecutive co per lane), cols = n (lane&15).
__global__ __launch_bounds__(256)
void conv1_mfma(const float* __restrict__ x, const long* __restrict__ w1p,
                const float* ax1, const float* __restrict__ s1b1,
                _Float16* __restrict__ qh1h) {
    const int tid = threadIdx.x;
    const int w = tid >> 6, l = tid & 63;
    const int quad = l >> 4, c16 = l & 15;
    const int n0 = blockIdx.x * 64, cs = blockIdx.y;
    const int n = n0 + w * 16 + c16;
    const int bi = n / 784, p = n - bi * 784;
    const float inv1 = 1.0f / ax1[0];       // exact for pow2 alpha

    // B-frags: on-the-fly quantized x, 8 channels per kc
    long bfr[3];
    #pragma unroll
    for (int kc = 0; kc < 3; ++kc) {
        const float* xs = x + (bi * 96 + kc * 32 + quad * 8) * 784 + p;
        unsigned long long v = 0;
        #pragma unroll
        for (int j = 0; j < 8; ++j) {
            float t = xs[j * 784] * inv1;
            t = fminf(fmaxf(t, -8.0f), 7.0f);
            int q = (int)rintf(t);
            v |= (unsigned long long)(q & 255) << (8 * j);
        }
        bfr[kc] = (long)v;
    }

    int4v acc[12];
    #pragma unroll
    for (int i = 0; i < 12; ++i) { acc[i][0] = 0; acc[i][1] = 0; acc[i][2] = 0; acc[i][3] = 0; }

    #pragma unroll
    for (int kc = 0; kc < 3; ++kc)
        #pragma unroll
        for (int ct = 0; ct < 12; ++ct)
            acc[ct] = __builtin_amdgcn_mfma_i32_16x16x32_i8(
                w1p[((cs * 12 + ct) * 3 + kc) * 64 + l], bfr[kc], acc[ct], 0, 0, 0);

    // epilogue: one FMA + clamp + rint per output; 4 consecutive co -> half4 store
    _Float16* orow = qh1h + n * 576;
    #pragma unroll
    for (int ct = 0; ct < 12; ++ct) {
        int co0 = cs * 192 + ct * 16 + quad * 4;
        float4v S = *(const float4v*)(s1b1 + co0);
        float4v B = *(const float4v*)(s1b1 + 576 + co0);
        half4 h;
        #pragma unroll
        for (int r = 0; r < 4; ++r) {
            float t = fmaf((float)acc[ct][r], S[r], B[r]);
            t = fminf(fmaxf(t, 0.0f), 7.0f);   // ReLU6-clamp and quant-clip fused
            h[r] = (_Float16)rintf(t);
        }
        *(half4*)(orow + co0) = h;
    }
}

// ---------------- dw: 3x3 depthwise in packed fp16 (exact int math) ----------------
// thread -> (n, g): 8 channels c = 8g..8g+7.  half8 loads, v_pk_fma_f16.
__global__ __launch_bounds__(256)
void dw_k(const _Float16* __restrict__ qh1h, const _Float16* __restrict__ w2h,
          const float* __restrict__ s2b2, signed char* __restrict__ qh2T) {
    int idx = blockIdx.x * 256 + threadIdx.x;   // 25088*72 exactly
    int n = idx / 72, g = idx - (idx / 72) * 72;
    int c0 = g * 8;
    int p = n % 784;
    int hh = p / 28, ww = p - hh * 28;
    const _Float16* base = qh1h + n * 576 + c0;

    half8 acc;
    #pragma unroll
    for (int j = 0; j < 8; ++j) acc[j] = (_Float16)0.0f;

    #pragma unroll
    for (int t = 0; t < 9; ++t) {
        const int dh = t / 3 - 1, dc = t % 3 - 1;
        int ih = hh + dh, iw = ww + dc;
        if (ih >= 0 && ih < 28 && iw >= 0 && iw < 28) {
            half8 xv = *(const half8*)(base + (dh * 28 + dc) * 576);
            half8 wv = *(const half8*)(w2h + t * 576 + c0);
            acc += xv * wv;                 // exact: |prod|<=64, |sum|<=576 < 2048
        }
    }

    int pk0 = 0, pk1 = 0;
    #pragma unroll
    for (int j = 0; j < 8; ++j) {
        int c = c0 + j;
        float t = fmaf((float)acc[j], s2b2[c], s2b2[576 + c]);
        t = fminf(fmaxf(t, 0.0f), 7.0f);
        int q = (int)rintf(t);
        if (j < 4) pk0 |= q << (8 * j);
        else       pk1 |= q << (8 * (j - 4));
    }
    int2v pk; pk[0] = pk0; pk[1] = pk1;
    *(int2v*)(qh2T + n * 576 + c0) = pk;
}

// ---------------- conv3: 1x1 project, i8 MFMA + fused BN + residual ----------------
// grid 1568 n-tiles of 16, block 384 (wave w = co-tile).  float4 residual I/O.
__global__ __launch_bounds__(384)
void conv3_mfma(const signed char* __restrict__ qh2T, const long* __restrict__ w3p,
                const float* __restrict__ x, const float* __restrict__ s3b3,
                float* __restrict__ out) {
    const int tid = threadIdx.x;
    const int w = tid >> 6, l = tid & 63;
    const int quad = l >> 4, c16 = l & 15;
    const int n0 = blockIdx.x * 16;
    const int n_m = n0 + c16;

    int4v acc;
    acc[0] = 0; acc[1] = 0; acc[2] = 0; acc[3] = 0;

    const signed char* arow = qh2T + n_m * 576 + quad * 8;
    #pragma unroll 6
    for (int kc = 0; kc < 18; ++kc) {
        long a = *(const long*)(arow + kc * 32);
        long b = w3p[(w * 18 + kc) * 64 + l];
        acc = __builtin_amdgcn_mfma_i32_16x16x32_i8(a, b, acc, 0, 0, 0);
    }

    const int co = w * 16 + c16;
    const float S = s3b3[co], B = s3b3[96 + co];
    const int nb = n0 + quad * 4;               // 4 consecutive n, same batch (784%16==0)
    const int bi = nb / 784, p0 = nb - bi * 784;
    const int off = (bi * 96 + co) * 784 + p0;
    float4v xr = *(const float4v*)(x + off);
    float4v o;
    #pragma unroll
    for (int r = 0; r < 4; ++r)
        o[r] = fmaf((float)acc[r], S, B) + xr[r];
    *(float4v*)(out + off) = o;
}

extern "C" void kernel_launch(void* const* d_in, const int* in_sizes, int n_in,
                              void* d_out, int out_size, void* d_ws, size_t ws_size,
                              hipStream_t stream) {
    const float* x   = (const float*)d_in[0];
    const float* w1  = (const float*)d_in[1];
    const float* w2  = (const float*)d_in[2];
    const float* w3  = (const float*)d_in[3];
    const float* aw1 = (const float*)d_in[4];
    const float* ax1 = (const float*)d_in[5];
    const float* g1  = (const float*)d_in[6];
    const float* b1  = (const float*)d_in[7];
    const float* m1  = (const float*)d_in[8];
    const float* v1  = (const float*)d_in[9];
    const float* aw2 = (const float*)d_in[10];
    const float* ax2 = (const float*)d_in[11];
    const float* g2  = (const float*)d_in[12];
    const float* b2  = (const float*)d_in[13];
    const float* m2  = (const float*)d_in[14];
    const float* v2  = (const float*)d_in[15];
    const float* aw3 = (const float*)d_in[16];
    const float* ax3 = (const float*)d_in[17];
    const float* g3  = (const float*)d_in[18];
    const float* b3  = (const float*)d_in[19];
    const float* m3  = (const float*)d_in[20];
    const float* v3  = (const float*)d_in[21];

    char* ws = (char*)d_ws;
    _Float16* qh1h = (_Float16*)(ws + QH1H_OFF);
    signed char* qh2T = (signed char*)(ws + QH2T_OFF);
    long* w1p = (long*)(ws + W1P_OFF);
    long* w3p = (long*)(ws + W3P_OFF);
    _Float16* w2h = (_Float16*)(ws + W2H_OFF);
    float* s1b1 = (float*)(ws + S1B1_OFF);
    float* s2b2 = (float*)(ws + S2B2_OFF);
    float* s3b3 = (float*)(ws + S3B3_OFF);

    float* out = (float*)d_out;

    prep_w<<<80, 256, 0, stream>>>(w1, w2, w3, aw1, ax1, ax2, aw2, ax3, aw3,
                                   g1, b1, m1, v1, g2, b2, m2, v2, g3, b3, m3, v3,
                                   w1p, w3p, w2h, s1b1, s2b2, s3b3);
    dim3 grid1(392, 3);
    conv1_mfma<<<grid1, 256, 0, stream>>>(x, w1p, ax1, s1b1, qh1h);
    dw_k<<<7056, 256, 0, stream>>>(qh1h, w2h, s2b2, qh2T);
    conv3_mfma<<<1568, 384, 0, stream>>>(qh2T, w3p, x, s3b3, out);
}